// Round 6
// baseline (946.278 us; speedup 1.0000x reference)
//
#include <hip/hip_runtime.h>
#include <stdint.h>

// Problem constants (B,T,C,H,N) = (4,960,2048,32,64)
#define BDIM 4
#define TDIM 960
#define CDIM 2048
#define HDIM 32
#define NDIM 64
#define BT   (BDIM*TDIM)   // 3840 rows

typedef unsigned short u16;
typedef __attribute__((ext_vector_type(8))) short short8;   // 8 bf16 (4 VGPRs)
typedef __attribute__((ext_vector_type(4))) float f32x4;

__device__ __forceinline__ float b2f(u16 u){
  union{unsigned int i; float f;}x; x.i=((unsigned int)u)<<16; return x.f;
}
__device__ __forceinline__ u16 f2b(float f){
  union{float f; unsigned int i;}x; x.f=f;
  unsigned int r = x.i + 0x7fffu + ((x.i>>16)&1u);   // RNE
  return (u16)(r>>16);
}
__device__ __forceinline__ void unpack8(uint4 p, float* o){
  o[0]=b2f((u16)(p.x&0xffff)); o[1]=b2f((u16)(p.x>>16));
  o[2]=b2f((u16)(p.y&0xffff)); o[3]=b2f((u16)(p.y>>16));
  o[4]=b2f((u16)(p.z&0xffff)); o[5]=b2f((u16)(p.z>>16));
  o[6]=b2f((u16)(p.w&0xffff)); o[7]=b2f((u16)(p.w>>16));
}
__device__ __forceinline__ uint4 pack8(const float* o){
  uint4 p;
  p.x = (unsigned)f2b(o[0]) | ((unsigned)f2b(o[1])<<16);
  p.y = (unsigned)f2b(o[2]) | ((unsigned)f2b(o[3])<<16);
  p.z = (unsigned)f2b(o[4]) | ((unsigned)f2b(o[5])<<16);
  p.w = (unsigned)f2b(o[6]) | ((unsigned)f2b(o[7])<<16);
  return p;
}
__device__ __forceinline__ void ld8f(const float* p, float* o){
  float4 a = *(const float4*)p;
  float4 b = *(const float4*)(p+4);
  o[0]=a.x;o[1]=a.y;o[2]=a.z;o[3]=a.w;o[4]=b.x;o[5]=b.y;o[6]=b.z;o[7]=b.w;
}
__device__ __forceinline__ float sigm(float x){ return 1.f/(1.f+expf(-x)); }
__device__ __forceinline__ void stc(float* p, float v){ *p = v; }
__device__ __forceinline__ void stc(u16* p, float v){ *p = f2b(v); }

// ---------------------------------------------------------------------------
// 0) fp32 -> bf16 weight conversion (one 2048x2048 matrix per launch)
__global__ __launch_bounds__(256) void cvt_kernel(const float* src, u16* dst){
  size_t i = ((size_t)blockIdx.x*256 + threadIdx.x)*8;
  float v[8]; ld8f(src+i, v);
  *(uint4*)(dst+i) = pack8(v);
}

// ---------------------------------------------------------------------------
// 1) batched transpose+pad+cvt for LoRA weights (tiny: <6 MB total)
struct TJob { const float* src; u16* dst; int R, Cs, DR, DC; };
struct TJobs8 { TJob j[8]; };

__global__ __launch_bounds__(256) void transpose_pad_kernel(TJobs8 jobs){
  TJob jb = jobs.j[blockIdx.z];
  int idx = blockIdx.x*256 + threadIdx.x;
  int total = jb.DR*jb.DC;
  if (idx >= total) return;
  int i = idx / jb.DC, k = idx % jb.DC;
  float v = 0.f;
  if (i < jb.Cs && k < jb.R) v = jb.src[(size_t)k*jb.Cs + i];
  jb.dst[idx] = f2b(v);
}

// ---------------------------------------------------------------------------
// 2) token-shift mixes: m = x + (x_prev - x)*coef  (6 bf16 outputs)
__global__ __launch_bounds__(256) void mix_kernel(
  const float* x,
  const float* cr, const float* cw, const float* ck,
  const float* cv, const float* ca, const float* cg,
  u16* mr, u16* mw, u16* mk, u16* mv, u16* ma, u16* mg)
{
  size_t tid = (size_t)blockIdx.x*256 + threadIdx.x;
  size_t base = tid*8;
  int c = (int)(base % CDIM);
  int row = (int)(base / CDIM);
  int t = row % TDIM;
  float xc[8], xp[8], xx[8], cf[8], o[8];
  ld8f(x+base, xc);
  if (t > 0) {
    ld8f(x+base-CDIM, xp);
  } else {
    for(int j=0;j<8;j++) xp[j]=0.f;
  }
  #pragma unroll
  for(int j=0;j<8;j++) xx[j]=xp[j]-xc[j];
#define DOMIX(CP, OP) do { ld8f(CP+c, cf); \
  _Pragma("unroll") for(int j=0;j<8;j++) o[j]=xc[j]+xx[j]*cf[j]; \
  *(uint4*)(OP+base)=pack8(o); } while(0)
  DOMIX(cr, mr); DOMIX(cw, mw); DOMIX(ck, mk);
  DOMIX(cv, mv); DOMIX(ca, ma); DOMIX(cg, mg);
#undef DOMIX
}

// ---------------------------------------------------------------------------
// 3) bf16 GEMM, C[M,N] = A[M,K] * Bt[N,K]^T  (B^T layout, m97 structure)
struct GemmJob {
  const u16* A; const u16* Bt; void* C;
  int nbm, nbn, K, lda, ldb, ldc;
};
struct GemmJobs { GemmJob j[4]; };

template<typename TC>
__global__ __launch_bounds__(256, 2) void gemm_bt_kernel(GemmJobs jobs){
  GemmJob jb = jobs.j[blockIdx.z];
  int bm = blockIdx.x % jb.nbm;
  int bn = blockIdx.x / jb.nbm;
  if (bn >= jb.nbn) return;
  __shared__ __attribute__((aligned(16))) u16 As[128*64];
  __shared__ __attribute__((aligned(16))) u16 Bs[128*64];
  int tid = threadIdx.x;
  int wave = tid>>6, lane = tid&63;
  int wr = wave>>1, wc = wave&1;
  f32x4 acc[4][4];
  #pragma unroll
  for(int i=0;i<4;i++)
    #pragma unroll
    for(int j=0;j<4;j++) acc[i][j] = (f32x4){0.f,0.f,0.f,0.f};
  const int rA0 = bm*128;
  const int rB0 = bn*128;
  int srow = (lane>>3);        // 0..7 row within 8-row slab
  int scol = (lane&7)*8;       // k element offset (8 bf16 = 16B)
  for (int k0=0; k0<jb.K; k0+=64){
    #pragma unroll
    for (int it=0; it<4; ++it){
      int rr = wave*32 + it*8;  // wave-uniform
      const u16* gA = jb.A + (size_t)(rA0 + rr + srow)*jb.lda + (k0 + scol);
      __builtin_amdgcn_global_load_lds((const __attribute__((address_space(1))) void*)gA,
          (__attribute__((address_space(3))) void*)&As[rr*64], 16, 0, 0);
      const u16* gB = jb.Bt + (size_t)(rB0 + rr + srow)*jb.ldb + (k0 + scol);
      __builtin_amdgcn_global_load_lds((const __attribute__((address_space(1))) void*)gB,
          (__attribute__((address_space(3))) void*)&Bs[rr*64], 16, 0, 0);
    }
    __syncthreads();
    #pragma unroll
    for (int kc=0; kc<2; ++kc){
      short8 af[4], bfr[4];
      int ko = kc*32 + (lane>>4)*8;
      #pragma unroll
      for (int mi=0; mi<4; ++mi)
        af[mi] = *(const short8*)&As[(wr*64 + mi*16 + (lane&15))*64 + ko];
      #pragma unroll
      for (int ni=0; ni<4; ++ni)
        bfr[ni] = *(const short8*)&Bs[(wc*64 + ni*16 + (lane&15))*64 + ko];
      #pragma unroll
      for (int mi=0; mi<4; ++mi)
        #pragma unroll
        for (int ni=0; ni<4; ++ni)
          acc[mi][ni] = __builtin_amdgcn_mfma_f32_16x16x32_bf16(af[mi], bfr[ni], acc[mi][ni], 0, 0, 0);
    }
    __syncthreads();
  }
  TC* C = (TC*)jb.C;
  int cn = (lane&15);
  int rq = (lane>>4)*4;
  #pragma unroll
  for (int mi=0; mi<4; ++mi){
    #pragma unroll
    for (int ni=0; ni<4; ++ni){
      int col = rB0 + wc*64 + ni*16 + cn;
      int row = rA0 + wr*64 + mi*16 + rq;
      #pragma unroll
      for (int e=0; e<4; ++e)
        stc(&C[(size_t)(row+e)*jb.ldc + col], acc[mi][ni][e]);
    }
  }
}

// ---------------------------------------------------------------------------
// 4) mid-LoRA activations
__global__ __launch_bounds__(256) void act_kernel(u16* hw, u16* hg){
  int idx = blockIdx.x*256 + threadIdx.x;
  if (blockIdx.z==0){ if (idx < BT*128) hw[idx] = f2b(tanhf(b2f(hw[idx]))); }
  else              { if (idx < BT*256) hg[idx] = f2b(sigm(b2f(hg[idx]))); }
}

// ---------------------------------------------------------------------------
// 5) post-GEMM elementwise. Emits PACKED scan planes:
//    P1[t,c] = (decay fp32, kfin bf16 | bsv bf16)  -- 8 B/col
//    P2[t,c] = (r bf16 | asv bf16)                 -- 4 B/col
//    plus KS (kfin) / VS (v final) bf16 planes for final_kernel.
__global__ __launch_bounds__(256) void post_kernel(
  const u16* kbuf, const u16* vraw, const float* vfirst, const u16* rbuf,
  const u16* wl, const u16* al, const u16* vl,
  const float* w0, const float* a0, const float* v0,
  const float* kkc, const float* kac,
  uint2* p1, unsigned* p2, u16* ks, u16* vs)
{
  int row = blockIdx.x, tid = threadIdx.x;
  int c = tid*8;
  size_t base = (size_t)row*CDIM + c;
  float kf[8], vr[8], vf[8], rf[8], wlf[8], alf[8], vlf[8], w0f[8], a0f[8], v0f[8], kkf[8], kaf[8];
  unpack8(*(const uint4*)(kbuf+base), kf);
  unpack8(*(const uint4*)(vraw+base), vr);
  ld8f(vfirst+base, vf);
  unpack8(*(const uint4*)(rbuf+base), rf);
  unpack8(*(const uint4*)(wl+base), wlf);
  unpack8(*(const uint4*)(al+base), alf);
  unpack8(*(const uint4*)(vl+base), vlf);
  ld8f(w0+c, w0f);
  ld8f(a0+c, a0f);
  ld8f(v0+c, v0f);
  ld8f(kkc+c, kkf);
  ld8f(kac+c, kaf);
  float dv[8], av[8], vv[8], kkr[8], kfin[8], asv[8], bsv[8];
  float ssq = 0.f;
  #pragma unroll
  for (int j=0;j<8;j++){
    float wv = -log1pf(expf(-(w0f[j]+wlf[j]))) - 0.5f;       // -softplus(-z)-0.5
    dv[j]  = expf(-expf(wv));                                // decay
    av[j]  = sigm(a0f[j]+alf[j]);
    vv[j]  = vr[j] + (vf[j]-vr[j])*sigm(v0f[j]+vlf[j]);
    kkr[j] = kf[j]*kkf[j];
    ssq   += kkr[j]*kkr[j];
    kfin[j]= kf[j]*(1.f + (av[j]-1.f)*kaf[j]);
  }
  ssq += __shfl_xor(ssq,1); ssq += __shfl_xor(ssq,2); ssq += __shfl_xor(ssq,4);
  float inv = 1.f/fmaxf(sqrtf(ssq), 1e-12f);
  #pragma unroll
  for (int j=0;j<8;j++){ float kkn = kkr[j]*inv; asv[j] = -kkn; bsv[j] = kkn*av[j]; }
  // P1: (d fp32, kfin|bsv) per col -> 4 uint4 stores
  unsigned w1[16];
  #pragma unroll
  for (int j=0;j<8;j++){
    union{float f; unsigned u;} du; du.f = dv[j];
    w1[2*j]   = du.u;
    w1[2*j+1] = (unsigned)f2b(kfin[j]) | ((unsigned)f2b(bsv[j])<<16);
  }
  uint4* o1 = (uint4*)(p1 + base);
  o1[0] = *(uint4*)&w1[0];  o1[1] = *(uint4*)&w1[4];
  o1[2] = *(uint4*)&w1[8];  o1[3] = *(uint4*)&w1[12];
  // P2: (r|asv) per col -> 2 uint4 stores
  unsigned w2[8];
  #pragma unroll
  for (int j=0;j<8;j++)
    w2[j] = (unsigned)f2b(rf[j]) | ((unsigned)f2b(asv[j])<<16);
  uint4* o2 = (uint4*)(p2 + base);
  o2[0] = *(uint4*)&w2[0];  o2[1] = *(uint4*)&w2[4];
  *(uint4*)(ks+base) = pack8(kfin);
  *(uint4*)(vs+base) = pack8(vv);
}

// ---------------------------------------------------------------------------
// 6) linear recurrence. 256 blocks (2 per head, 32 rows each), 256 threads:
// thread (ii=row 0..31, jg=colgrp 0..7) holds 8 fp32 state cols. 16 steps per
// barrier; staging via global_load_lds (width 16) from PRE-PACKED planes,
// double-buffered: group g+1's loads issued before computing group g.
// LDS per buffer: P1 16*512=8192 | P2 16*256=4096 | V 16*64=1024 -> 13312 B
__global__ __launch_bounds__(256) void scan_kernel(
  const uint2* p1g, const unsigned* p2g, const u16* vg, float* yb)
{
  __shared__ __attribute__((aligned(16))) char lds[2*13312];
  int blk = blockIdx.x;
  int b    = blk >> 6;
  int h    = (blk >> 1) & 31;
  int half = blk & 1;
  int tid = threadIdx.x;
  int jg = tid & 7;
  int ii = tid >> 3;
  int row = half*32 + ii;
  int wave = tid >> 6, lane = tid & 63;
  size_t hb = ((size_t)b*TDIM)*CDIM + (size_t)h*NDIM;

  float S[8];
  #pragma unroll
  for (int e=0;e<8;e++) S[e]=0.f;

  auto stage = [&](int p, int t0){
    char* dst = lds + p*13312;
    #pragma unroll
    for (int i2=0;i2<2;++i2){
      int i = wave*2 + i2;      // instr i covers steps 2i,2i+1 (512 B each)
      const uint2* g = p1g + hb + (size_t)(t0 + 2*i + (lane>>5))*CDIM + (lane&31)*2;
      __builtin_amdgcn_global_load_lds((const __attribute__((address_space(1))) void*)g,
        (__attribute__((address_space(3))) void*)(dst + i*1024), 16, 0, 0);
    }
    {
      // instr w covers steps 4w..4w+3 (256 B each)
      const unsigned* g = p2g + hb + (size_t)(t0 + 4*wave + (lane>>4))*CDIM + (lane&15)*4;
      __builtin_amdgcn_global_load_lds((const __attribute__((address_space(1))) void*)g,
        (__attribute__((address_space(3))) void*)(dst + 8192 + wave*1024), 16, 0, 0);
    }
    if (wave==0){
      // 16 steps x 32 rows x 2 B = 1 KB; lane covers 8 v-values
      const u16* g = vg + hb + (size_t)(t0 + (lane>>2))*CDIM + half*32 + (lane&3)*8;
      __builtin_amdgcn_global_load_lds((const __attribute__((address_space(1))) void*)g,
        (__attribute__((address_space(3))) void*)(dst + 12288), 16, 0, 0);
    }
  };

  stage(0, 0);
  __syncthreads();
  int p = 0;
  for (int g=0; g<60; ++g){
    if (g+1 < 60) stage(p^1, (g+1)*16);
    const char* buf = lds + p*13312;
    #pragma unroll
    for (int s=0; s<16; ++s){
      uint4 x0 = *(const uint4*)(buf + s*512 + jg*64);
      uint4 x1 = *(const uint4*)(buf + s*512 + jg*64 + 16);
      uint4 x2 = *(const uint4*)(buf + s*512 + jg*64 + 32);
      uint4 x3 = *(const uint4*)(buf + s*512 + jg*64 + 48);
      uint4 y0 = *(const uint4*)(buf + 8192 + s*256 + jg*32);
      uint4 y1 = *(const uint4*)(buf + 8192 + s*256 + jg*32 + 16);
      u16 vraw = *(const u16*)(buf + 12288 + s*64 + ii*2);
      float vi = b2f(vraw);
      float d[8], kk[8], bb[8], qq[8], aa[8];
      d[0]=__uint_as_float(x0.x); kk[0]=__uint_as_float(x0.y<<16); bb[0]=__uint_as_float(x0.y&0xffff0000u);
      d[1]=__uint_as_float(x0.z); kk[1]=__uint_as_float(x0.w<<16); bb[1]=__uint_as_float(x0.w&0xffff0000u);
      d[2]=__uint_as_float(x1.x); kk[2]=__uint_as_float(x1.y<<16); bb[2]=__uint_as_float(x1.y&0xffff0000u);
      d[3]=__uint_as_float(x1.z); kk[3]=__uint_as_float(x1.w<<16); bb[3]=__uint_as_float(x1.w&0xffff0000u);
      d[4]=__uint_as_float(x2.x); kk[4]=__uint_as_float(x2.y<<16); bb[4]=__uint_as_float(x2.y&0xffff0000u);
      d[5]=__uint_as_float(x2.z); kk[5]=__uint_as_float(x2.w<<16); bb[5]=__uint_as_float(x2.w&0xffff0000u);
      d[6]=__uint_as_float(x3.x); kk[6]=__uint_as_float(x3.y<<16); bb[6]=__uint_as_float(x3.y&0xffff0000u);
      d[7]=__uint_as_float(x3.z); kk[7]=__uint_as_float(x3.w<<16); bb[7]=__uint_as_float(x3.w&0xffff0000u);
      qq[0]=__uint_as_float(y0.x<<16); aa[0]=__uint_as_float(y0.x&0xffff0000u);
      qq[1]=__uint_as_float(y0.y<<16); aa[1]=__uint_as_float(y0.y&0xffff0000u);
      qq[2]=__uint_as_float(y0.z<<16); aa[2]=__uint_as_float(y0.z&0xffff0000u);
      qq[3]=__uint_as_float(y0.w<<16); aa[3]=__uint_as_float(y0.w&0xffff0000u);
      qq[4]=__uint_as_float(y1.x<<16); aa[4]=__uint_as_float(y1.x&0xffff0000u);
      qq[5]=__uint_as_float(y1.y<<16); aa[5]=__uint_as_float(y1.y&0xffff0000u);
      qq[6]=__uint_as_float(y1.z<<16); aa[6]=__uint_as_float(y1.z&0xffff0000u);
      qq[7]=__uint_as_float(y1.w<<16); aa[7]=__uint_as_float(y1.w&0xffff0000u);
      float sap = S[0]*aa[0]+S[1]*aa[1]+S[2]*aa[2]+S[3]*aa[3]
                + S[4]*aa[4]+S[5]*aa[5]+S[6]*aa[6]+S[7]*aa[7];
      sap += __shfl_xor(sap,1);
      sap += __shfl_xor(sap,2);
      sap += __shfl_xor(sap,4);
      float yp = 0.f;
      #pragma unroll
      for (int e=0;e<8;e++){
        S[e] = S[e]*d[e] + sap*bb[e] + vi*kk[e];
        yp  += S[e]*qq[e];
      }
      yp += __shfl_xor(yp,1);
      yp += __shfl_xor(yp,2);
      yp += __shfl_xor(yp,4);
      if (jg==0) yb[hb + (size_t)(g*16+s)*CDIM + row] = yp;
    }
    __syncthreads();
    p ^= 1;
  }
}

// ---------------------------------------------------------------------------
// 7) GroupNorm + bonus term + *g  -> bf16 YG
__global__ __launch_bounds__(256) void final_kernel(
  const float* yb, const u16* rb, const u16* ks, const u16* vs,
  const float* rk, const float* lnw, const float* lnb, const u16* gl, u16* yg)
{
  int row = blockIdx.x, tid = threadIdx.x;
  int c = tid*8;
  size_t base = (size_t)row*CDIM + c;
  float y[8], rf[8], kf[8], vf[8], rkf[8], lw[8], lb[8], gf[8];
  ld8f(yb+base, y);
  unpack8(*(const uint4*)(rb+base), rf);
  unpack8(*(const uint4*)(ks+base), kf);
  unpack8(*(const uint4*)(vs+base), vf);
  ld8f(rk+c,  rkf);
  ld8f(lnw+c, lw);
  ld8f(lnb+c, lb);
  unpack8(*(const uint4*)(gl+base), gf);
  float sy=0.f, syy=0.f, coef=0.f;
  #pragma unroll
  for (int j=0;j<8;j++){ sy+=y[j]; syy+=y[j]*y[j]; coef += rf[j]*kf[j]*rkf[j]; }
  sy  += __shfl_xor(sy,1);  sy  += __shfl_xor(sy,2);  sy  += __shfl_xor(sy,4);
  syy += __shfl_xor(syy,1); syy += __shfl_xor(syy,2); syy += __shfl_xor(syy,4);
  coef+= __shfl_xor(coef,1);coef+= __shfl_xor(coef,2);coef+= __shfl_xor(coef,4);
  float mu  = sy*(1.f/64.f);
  float var = syy*(1.f/64.f) - mu*mu;
  float rs  = rsqrtf(var + 6.4e-4f);    // EPS_GN = 1e-5*64
  float o[8];
  #pragma unroll
  for (int j=0;j<8;j++)
    o[j] = (((y[j]-mu)*rs)*lw[j] + lb[j] + coef*vf[j]) * gf[j];
  *(uint4*)(yg+base) = pack8(o);
}

// ---------------------------------------------------------------------------
extern "C" void kernel_launch(void* const* d_in, const int* in_sizes, int n_in,
                              void* d_out, int out_size, void* d_ws, size_t ws_size,
                              hipStream_t stream)
{
  const float* x      = (const float*)d_in[0];
  const float* vfirst = (const float*)d_in[1];
  const float* c_r = (const float*)d_in[2];
  const float* c_w = (const float*)d_in[3];
  const float* c_k = (const float*)d_in[4];
  const float* c_v = (const float*)d_in[5];
  const float* c_a = (const float*)d_in[6];
  const float* c_g = (const float*)d_in[7];
  const float* w0i = (const float*)d_in[8];
  const float* w1i = (const float*)d_in[9];
  const float* w2i = (const float*)d_in[10];
  const float* a0i = (const float*)d_in[11];
  const float* a1i = (const float*)d_in[12];
  const float* a2i = (const float*)d_in[13];
  const float* v0i = (const float*)d_in[14];
  const float* v1i = (const float*)d_in[15];
  const float* v2i = (const float*)d_in[16];
  const float* g1i = (const float*)d_in[17];
  const float* g2i = (const float*)d_in[18];
  const float* kki = (const float*)d_in[19];
  const float* kai = (const float*)d_in[20];
  const float* rki = (const float*)d_in[21];
  const float* Wr  = (const float*)d_in[22];
  const float* Wk  = (const float*)d_in[23];
  const float* Wv  = (const float*)d_in[24];
  const float* Wo  = (const float*)d_in[25];
  const float* lnw = (const float*)d_in[26];
  const float* lnb = (const float*)d_in[27];

  char* ws = (char*)d_ws;
  const size_t S2 = (size_t)BT*CDIM*2;    // bf16 [BT,C] plane = 15,728,640 B
  // bf16 mix planes [0, 6*S2)
  u16* MIXR = (u16*)(ws + 0*S2);
  u16* MIXW = (u16*)(ws + 1*S2);
  u16* MIXK = (u16*)(ws + 2*S2);
  u16* MIXV = (u16*)(ws + 3*S2);
  u16* MIXA = (u16*)(ws + 4*S2);
  u16* MIXG = (u16*)(ws + 5*S2);
  // bf16 projection outputs
  u16* RBUF = (u16*)(ws + 6*S2);
  u16* KBUF = (u16*)(ws + 7*S2);
  u16* VRAW = (u16*)(ws + 8*S2);
  // dedicated Wo bf16 slot (converted once at stage 0)
  char* WB = ws + 9*S2;
  u16* WoB = (u16*)WB;              // 8,388,608 B
  char* WT = WB + 8388608;
  u16* W1T = (u16*)(WT + 0);        // [128,2048]
  u16* A1T = (u16*)(WT + 524288);
  u16* V1T = (u16*)(WT + 1048576);
  u16* G1T = (u16*)(WT + 1572864);  // [256,2048]
  u16* W2T = (u16*)(WT + 2621440);  // [2048,128]
  u16* A2T = (u16*)(WT + 3145728);
  u16* V2T = (u16*)(WT + 3670016);
  u16* G2T = (u16*)(WT + 4194304);  // [2048,256]
  char* HB = WT + 5242880;
  u16* HW = (u16*)(HB + 0);         // [BT,128]
  u16* HA = (u16*)(HB + 983040);
  u16* HV = (u16*)(HB + 1966080);
  u16* HG = (u16*)(HB + 2949120);   // [BT,256]
  char* L2 = HB + 4915200;
  u16* WL = (u16*)(L2 + 0*S2);
  u16* AL = (u16*)(L2 + 1*S2);
  u16* VL = (u16*)(L2 + 2*S2);
  u16* GL = (u16*)(L2 + 3*S2);      // ws end = L2 + 4*S2 = 223,019,008 B (~212.7 MiB)
  // aliases (producers strictly after last consumer of the dead buffers):
  u16* WrB = (u16*)(L2 + 0);            // over WL/AL region; dead before stage 6
  u16* WkB = (u16*)(L2 + 8388608);
  u16* WvB = (u16*)(L2 + 16777216);
  uint2*    P1 = (uint2*)(ws + 0*S2);   // 4 planes over MIXR..MIXV (dead after stage 4)
  unsigned* P2 = (unsigned*)(ws + 4*S2);// 2 planes over MIXA+MIXG
  u16* KS = (u16*)(L2 + 0*S2);          // elementwise over WL (read-then-write in post)
  u16* VS = (u16*)(L2 + 1*S2);          // elementwise over AL
  float* YBUF = (float*)(ws + 7*S2);    // fp32, 2 planes over KBUF+VRAW (dead after stage 7)
  u16* YG = (u16*)(L2 + 2*S2);          // over VL (dead after stage 7)
  (void)in_sizes; (void)n_in; (void)out_size; (void)ws_size;

  // 0) convert big weights fp32 -> bf16 (r/k/v into L2-region aliases, Wo dedicated)
  cvt_kernel<<<dim3(2048), 256, 0, stream>>>(Wr, WrB);
  cvt_kernel<<<dim3(2048), 256, 0, stream>>>(Wk, WkB);
  cvt_kernel<<<dim3(2048), 256, 0, stream>>>(Wv, WvB);
  cvt_kernel<<<dim3(2048), 256, 0, stream>>>(Wo, WoB);

  // 1) transpose+pad+cvt LoRA weights
  TJobs8 tj;
  tj.j[0] = (TJob){w1i, W1T, 2048,  96, 128, 2048};
  tj.j[1] = (TJob){a1i, A1T, 2048,  96, 128, 2048};
  tj.j[2] = (TJob){v1i, V1T, 2048,  64, 128, 2048};
  tj.j[3] = (TJob){g1i, G1T, 2048, 256, 256, 2048};
  tj.j[4] = (TJob){w2i, W2T,   96, 2048, 2048, 128};
  tj.j[5] = (TJob){a2i, A2T,   96, 2048, 2048, 128};
  tj.j[6] = (TJob){v2i, V2T,   64, 2048, 2048, 128};
  tj.j[7] = (TJob){g2i, G2T,  256, 2048, 2048, 256};
  transpose_pad_kernel<<<dim3(2048,1,8), 256, 0, stream>>>(tj);

  // 2) token-shift mixes (fp32 in, bf16 out)
  mix_kernel<<<dim3(BT*CDIM/8/256), 256, 0, stream>>>(
      x, c_r, c_w, c_k, c_v, c_a, c_g, MIXR, MIXW, MIXK, MIXV, MIXA, MIXG);

  // 3) big projections r,k,v — ONE batched launch, 1440 blocks
  GemmJobs gj;
  gj.j[0] = (GemmJob){MIXR, WrB, RBUF, 30, 16, 2048, 2048, 2048, 2048};
  gj.j[1] = (GemmJob){MIXK, WkB, KBUF, 30, 16, 2048, 2048, 2048, 2048};
  gj.j[2] = (GemmJob){MIXV, WvB, VRAW, 30, 16, 2048, 2048, 2048, 2048};
  gj.j[3] = gj.j[0];
  gemm_bt_kernel<u16><<<dim3(480,1,3), 256, 0, stream>>>(gj);

  // 4) LoRA first halves (bf16 C)
  GemmJobs lj1;
  lj1.j[0] = (GemmJob){MIXW, W1T, HW, 30, 1, 2048, 2048, 2048, 128};
  lj1.j[1] = (GemmJob){MIXA, A1T, HA, 30, 1, 2048, 2048, 2048, 128};
  lj1.j[2] = (GemmJob){MIXV, V1T, HV, 30, 1, 2048, 2048, 2048, 128};
  lj1.j[3] = (GemmJob){MIXG, G1T, HG, 30, 2, 2048, 2048, 2048, 256};
  gemm_bt_kernel<u16><<<dim3(60,1,4), 256, 0, stream>>>(lj1);

  // 5) mid activations
  act_kernel<<<dim3(3840,1,2), 256, 0, stream>>>(HW, HG);

  // 6) LoRA second halves (bf16 C)
  GemmJobs lj2;
  lj2.j[0] = (GemmJob){HW, W2T, WL, 30, 16, 128, 128, 128, 2048};
  lj2.j[1] = (GemmJob){HA, A2T, AL, 30, 16, 128, 128, 128, 2048};
  lj2.j[2] = (GemmJob){HV, V2T, VL, 30, 16, 128, 128, 128, 2048};
  lj2.j[3] = (GemmJob){HG, G2T, GL, 30, 16, 256, 256, 256, 2048};
  gemm_bt_kernel<u16><<<dim3(480,1,4), 256, 0, stream>>>(lj2);

  // 7) post elementwise -> packed scan planes + KS/VS
  post_kernel<<<dim3(BT), 256, 0, stream>>>(
      KBUF, VRAW, vfirst, RBUF, WL, AL, VL, w0i, a0i, v0i, kki, kai,
      P1, P2, KS, VS);

  // 8) recurrence
  scan_kernel<<<dim3(256), 256, 0, stream>>>(P1, P2, VS, YBUF);

  // 9) GroupNorm + bonus + *g -> bf16 YG
  final_kernel<<<dim3(BT), 256, 0, stream>>>(
      YBUF, RBUF, KS, VS, rki, lnw, lnb, GL, YG);

  // 10) output projection (fp32 C = d_out)
  GemmJobs oj;
  oj.j[0] = (GemmJob){YG, WoB, d_out, 30, 16, 2048, 2048, 2048, 2048};
  oj.j[1] = oj.j[0]; oj.j[2] = oj.j[0]; oj.j[3] = oj.j[0];
  gemm_bt_kernel<float><<<dim3(480,1,1), 256, 0, stream>>>(oj);
}